// Round 9
// baseline (272.204 us; speedup 1.0000x reference)
//
#include <hip/hip_runtime.h>
#include <stdint.h>

// Problem constants (fixed by the reference)
constexpr int NN = 131072;          // coarse nodes
constexpr int EE = 1048576;         // edges
constexpr int NF = 4 * NN;          // fine nodes = 524288
constexpr int KK = 3 * NF;          // unpool entries = 1572864

constexpr int NBLK = 64;            // sort blocks per side (1024 threads each)
constexpr int TPS  = 1024;          // threads per sort block
constexpr int SH_E = 6;             // 64 nodes/bin  -> 2048 bins (E side)
constexpr int SH_K = 7;             // 128 nodes/bin -> 4096 bins (K side)
constexpr int NB_E = NN >> SH_E;    // 2048
constexpr int NB_K = NF >> SH_K;    // 4096
constexpr int EPT_E = EE / NBLK / TPS;  // 16 edges/thread
constexpr int EPT_K = KK / NBLK / TPS;  // 24 entries/thread
constexpr int CAP_E = 2048;         // >> mean 512 + 10 sigma
constexpr int CAP_K = 1024;         // >> mean 384 + 10 sigma
constexpr int KOFF = NB_E * NBLK;       // K hist offset in combined array
constexpr int NH   = NB_E * NBLK + NB_K * NBLK;  // 393,216
constexpr int NSCB = NH / 2048;         // 192 scan blocks
constexpr int NTRB = NN / 32 / 4;       // 1024 transpose blocks (4 tiles each)

typedef __attribute__((ext_vector_type(8))) short bf16x8;
typedef __attribute__((ext_vector_type(4))) float f32x4;

__device__ inline uint32_t bf16rn(float f) {
    uint32_t u = __float_as_uint(f);
    return (u + 0x7FFFu + ((u >> 16) & 1u)) >> 16;
}
__device__ inline uint32_t pack2(float lo, float hi) {
    return bf16rn(lo) | (bf16rn(hi) << 16);
}
__device__ inline float bf_lo(uint32_t v) { return __uint_as_float(v << 16); }
__device__ inline float bf_hi(uint32_t v) { return __uint_as_float(v & 0xFFFF0000u); }

// ---------------------------------------------------------------------------
// 1) Fused: transpose (blocks 0..NTRB-1, 4 tiles each) + pass1 histograms
//    (blocks NTRB..NTRB+127). LDS union: tile (16.9 KB) / hist (16 KB).
// ---------------------------------------------------------------------------
template<int NB, int EPT>
__device__ void pass1_body(const int* __restrict__ idx, int shift,
                           int* __restrict__ histG, int blk, int* hist)
{
    for (int f = threadIdx.x; f < NB; f += TPS) hist[f] = 0;
    __syncthreads();
    int base = blk * (TPS * EPT);
#pragma unroll
    for (int u = 0; u < EPT; ++u) {
        int b = idx[base + u * TPS + threadIdx.x] >> shift;
        atomicAdd(&hist[b], 1);
    }
    __syncthreads();
    for (int f = threadIdx.x; f < NB; f += TPS)
        histG[f * NBLK + blk] = hist[f];
}

__global__ __launch_bounds__(1024) void k_fused1(
    const float* __restrict__ a, const float* __restrict__ b,
    uint32_t* __restrict__ xTb,
    const int* __restrict__ reduce_i, const int* __restrict__ up_dst,
    int* __restrict__ histG)
{
    __shared__ int smem[128 * 33];   // union: float tile[128][33] / hist[NB_K]
    if (blockIdx.x < NTRB) {
        float (*tile)[33] = (float (*)[33])smem;
        for (int t = 0; t < 4; ++t) {
            int i0 = (blockIdx.x * 4 + t) * 32;
            for (int f = threadIdx.x; f < 128 * 32; f += TPS) {
                int c = f >> 5, j = f & 31;
                const float* src = (c < 64) ? a : b;
                tile[c][j] = src[(size_t)(c & 63) * NN + i0 + j];
            }
            __syncthreads();
            for (int f = threadIdx.x; f < 64 * 32; f += TPS) {
                int p = f & 63, j = f >> 6;
                xTb[(size_t)(i0 + j) * 64 + p] =
                    pack2(tile[2 * p][j], tile[2 * p + 1][j]);
            }
            __syncthreads();
        }
    } else if (blockIdx.x < NTRB + NBLK) {
        pass1_body<NB_E, EPT_E>(reduce_i, SH_E, histG, blockIdx.x - NTRB, smem);
    } else {
        pass1_body<NB_K, EPT_K>(up_dst, SH_K, histG + KOFF,
                                blockIdx.x - NTRB - NBLK, smem);
    }
}

// ---------------------------------------------------------------------------
// 2) Scan: block sums over 2048-chunks, then fused final scan
// ---------------------------------------------------------------------------
__global__ __launch_bounds__(256) void k_bsum(
    const int* __restrict__ cnt, int* __restrict__ bsum)
{
    __shared__ int s[256];
    int base = blockIdx.x * 2048;
    int sum = 0;
    for (int j = threadIdx.x; j < 2048; j += 256) sum += cnt[base + j];
    s[threadIdx.x] = sum;
    __syncthreads();
    for (int o = 128; o > 0; o >>= 1) {
        if (threadIdx.x < o) s[threadIdx.x] += s[threadIdx.x + o];
        __syncthreads();
    }
    if (threadIdx.x == 0) bsum[blockIdx.x] = s[0];
}

__global__ __launch_bounds__(256) void k_final(
    int* __restrict__ offs, const int* __restrict__ bsum)
{
    __shared__ int ts[256];
    int partial = 0;
    for (int i = threadIdx.x; i < blockIdx.x; i += 256) partial += bsum[i];
    ts[threadIdx.x] = partial;
    __syncthreads();
    for (int o = 128; o > 0; o >>= 1) {
        if (threadIdx.x < o) ts[threadIdx.x] += ts[threadIdx.x + o];
        __syncthreads();
    }
    int bb = ts[0];
    __syncthreads();

    int base = blockIdx.x * 2048 + threadIdx.x * 8;
    int loc[8];
    int sum = 0;
#pragma unroll
    for (int u = 0; u < 8; ++u) {
        int v = offs[base + u];
        loc[u] = sum;
        sum += v;
    }
    ts[threadIdx.x] = sum;
    __syncthreads();
    for (int o = 1; o < 256; o <<= 1) {
        int v = (threadIdx.x >= o) ? ts[threadIdx.x - o] : 0;
        __syncthreads();
        ts[threadIdx.x] += v;
        __syncthreads();
    }
    int texc = (threadIdx.x == 0) ? 0 : ts[threadIdx.x - 1];
#pragma unroll
    for (int u = 0; u < 8; ++u) offs[base + u] = bb + texc + loc[u];
    if (blockIdx.x == gridDim.x - 1 && threadIdx.x == 255) offs[NH] = bb + ts[255];
}

// ---------------------------------------------------------------------------
// 3) pass2: scatter packed pairs. 64 blocks/side x 1024 threads -> runs of
//    ~8 entries per (bin,block) = 32 B -> write amp ~2x (was ~8x).
//    pack: payload (17 bits) | bucket-local (<<17)
// ---------------------------------------------------------------------------
template<int NB, int EPT>
__device__ void pass2_body(const int* __restrict__ idx,
                           const int* __restrict__ payload, int shift,
                           const int* __restrict__ offsG, int sub,
                           uint32_t* __restrict__ pairs, int blk, int* curs)
{
    for (int f = threadIdx.x; f < NB; f += TPS)
        curs[f] = offsG[f * NBLK + blk] - sub;
    __syncthreads();
    int lmask = (1 << shift) - 1;
    int base = blk * (TPS * EPT);
#pragma unroll
    for (int u = 0; u < EPT; ++u) {
        int e = base + u * TPS + threadIdx.x;
        int bk = idx[e];
        int pos = atomicAdd(&curs[bk >> shift], 1);
        pairs[pos] = (uint32_t)payload[e] | ((uint32_t)(bk & lmask) << 17);
    }
}

__global__ __launch_bounds__(1024) void k_pass2(
    const int* __restrict__ reduce_i, const int* __restrict__ gather_i,
    const int* __restrict__ up_dst, const int* __restrict__ up_src,
    const int* __restrict__ offs,
    uint32_t* __restrict__ pairsE, uint32_t* __restrict__ pairsK)
{
    __shared__ int curs[NB_K];   // 16 KB
    if (blockIdx.x < NBLK)
        pass2_body<NB_E, EPT_E>(reduce_i, gather_i, SH_E, offs, 0,
                                pairsE, blockIdx.x, curs);
    else
        pass2_body<NB_K, EPT_K>(up_dst, up_src, SH_K, offs + KOFF, EE,
                                pairsK, blockIdx.x - NBLK, curs);
}

// ---------------------------------------------------------------------------
// 4) Bin-wise aggregation: in-LDS counting sort, 16-deep entry-stream MLP,
//    flush-on-node-change, register accumulate, write-once.
// ---------------------------------------------------------------------------
__global__ __launch_bounds__(256) void k_aggcsr(
    const uint32_t* __restrict__ xTb, const int* __restrict__ offsE,
    const uint32_t* __restrict__ pairsE, uint32_t* __restrict__ aggB)
{
    __shared__ uint32_t list[CAP_E];
    __shared__ int offs[65];
    __shared__ int curs[64];
    __shared__ int cnt_s;
    int bin = blockIdx.x;
    if (threadIdx.x == 0) {
        int beg = offsE[bin * NBLK];
        cnt_s = min(offsE[(bin + 1) * NBLK] - beg, CAP_E);
    }
    if (threadIdx.x < 64) curs[threadIdx.x] = 0;
    __syncthreads();
    int beg = offsE[bin * NBLK];
    int cnt = cnt_s;
    for (int i = threadIdx.x; i < cnt; i += 256)
        atomicAdd(&curs[(pairsE[beg + i] >> 17) & 63], 1);
    __syncthreads();
    if (threadIdx.x == 0) {
        int run = 0;
        for (int j = 0; j < 64; ++j) {
            offs[j] = run;
            run += curs[j];
            curs[j] = offs[j];
        }
        offs[64] = run;
    }
    __syncthreads();
    for (int i = threadIdx.x; i < cnt; i += 256) {
        uint32_t u = pairsE[beg + i];
        int p = atomicAdd(&curs[(u >> 17) & 63], 1);
        list[p] = u;
    }
    __syncthreads();

    int w = threadIdx.x >> 6, lane = threadIdx.x & 63;
    int n0 = w * 16, n1 = n0 + 16;
    int e0 = offs[n0], e1 = offs[n1];
    size_t rowbase = (size_t)(bin * 64) * 64 + lane;
    float sx = 0.f, sy = 0.f;
    int cur = n0;
    for (int e = e0; e < e1; e += 16) {
        int nb = e1 - e;
        uint32_t pr[16], v[16];
#pragma unroll
        for (int j = 0; j < 16; ++j)
            pr[j] = list[e + ((j < nb) ? j : (nb - 1))];
#pragma unroll
        for (int j = 0; j < 16; ++j)
            v[j] = xTb[(size_t)(pr[j] & 0x1FFFF) * 64 + lane];
#pragma unroll
        for (int j = 0; j < 16; ++j) {
            if (j < nb) {
                int d = (pr[j] >> 17) & 63;
                if (d != cur) {
                    aggB[rowbase + (size_t)cur * 64] = pack2(sx, sy);
                    for (int z = cur + 1; z < d; ++z)
                        aggB[rowbase + (size_t)z * 64] = 0u;
                    cur = d;
                    sx = 0.f; sy = 0.f;
                }
                sx += bf_lo(v[j]);
                sy += bf_hi(v[j]);
            }
        }
    }
    aggB[rowbase + (size_t)cur * 64] = pack2(sx, sy);
    for (int z = cur + 1; z < n1; ++z)
        aggB[rowbase + (size_t)z * 64] = 0u;
}

// ---------------------------------------------------------------------------
// 5) MFMA GEMM: h = relu([Wself|Wneigh] @ [x;agg] + bias), bf16 in/out.
//    C/D: col(node)=l&15, row(c)=(l>>4)*4+r  [m89-verified layout]
// ---------------------------------------------------------------------------
__global__ __launch_bounds__(256) void k_gemm(
    const uint32_t* __restrict__ xTb, const uint32_t* __restrict__ aggB,
    const float* __restrict__ Wself, const float* __restrict__ Wneigh,
    const float* __restrict__ bias, uint32_t* __restrict__ hT)
{
    int lane = threadIdx.x & 63;
    int wid = blockIdx.x * 4 + (threadIdx.x >> 6);
    int lr = lane & 15, lq = lane >> 4;

    bf16x8 wf[4][8];
#pragma unroll
    for (int mt = 0; mt < 4; ++mt) {
#pragma unroll
        for (int kt = 0; kt < 8; ++kt) {
            const float* W = (kt < 4) ? Wself : Wneigh;
            const float* p = W + (size_t)(mt * 16 + lr) * 128 + (kt & 3) * 32 + lq * 8;
            bf16x8 v;
#pragma unroll
            for (int j = 0; j < 8; ++j) v[j] = (short)bf16rn(p[j]);
            wf[mt][kt] = v;
        }
    }
    float bv[4][4];
#pragma unroll
    for (int mt = 0; mt < 4; ++mt)
#pragma unroll
        for (int r = 0; r < 4; ++r)
            bv[mt][r] = bias[mt * 16 + lq * 4 + r];

    const int NG = NN / 16;
    int stride = gridDim.x * 4;
    for (int g = wid; g < NG; g += stride) {
        int n = g * 16 + lr;
        const uint32_t* xr = xTb + (size_t)n * 64 + lq * 4;
        const uint32_t* ar = aggB + (size_t)n * 64 + lq * 4;
        bf16x8 bq[8];
#pragma unroll
        for (int kt = 0; kt < 4; ++kt)
            bq[kt] = *reinterpret_cast<const bf16x8*>(xr + kt * 16);
#pragma unroll
        for (int kt = 0; kt < 4; ++kt)
            bq[4 + kt] = *reinterpret_cast<const bf16x8*>(ar + kt * 16);
#pragma unroll
        for (int mt = 0; mt < 4; ++mt) {
            f32x4 acc = {0.f, 0.f, 0.f, 0.f};
#pragma unroll
            for (int kt = 0; kt < 8; ++kt)
                acc = __builtin_amdgcn_mfma_f32_16x16x32_bf16(wf[mt][kt], bq[kt], acc, 0, 0, 0);
            uint32_t u0 = pack2(fmaxf(acc[0] + bv[mt][0], 0.f), fmaxf(acc[1] + bv[mt][1], 0.f));
            uint32_t u1 = pack2(fmaxf(acc[2] + bv[mt][2], 0.f), fmaxf(acc[3] + bv[mt][3], 0.f));
            *reinterpret_cast<uint2*>(hT + (size_t)n * 32 + mt * 8 + lq * 2) = make_uint2(u0, u1);
        }
    }
}

// ---------------------------------------------------------------------------
// 6) Bin-wise unpool: in-LDS counting sort, 16-deep entry-stream MLP,
//    register bit-max (bf16 >= 0), pre-zeroed LDS buf, coalesced epilogue.
// ---------------------------------------------------------------------------
__global__ __launch_bounds__(256) void k_unpoolcsr(
    const uint16_t* __restrict__ hT16, const int* __restrict__ offsK,
    const uint32_t* __restrict__ pairsK, float* __restrict__ out)
{
    __shared__ uint32_t list[CAP_K];
    __shared__ int offs[129];
    __shared__ int curs[128];
    __shared__ uint16_t buf[128][65];
    __shared__ int cnt_s;
    int bin = blockIdx.x;
    if (threadIdx.x == 0) {
        int beg = offsK[bin * NBLK] - EE;
        cnt_s = min(offsK[(bin + 1) * NBLK] - EE - beg, CAP_K);
    }
    if (threadIdx.x < 128) curs[threadIdx.x] = 0;
    for (int f = threadIdx.x; f < 128 * 65; f += 256) ((uint16_t*)buf)[f] = 0;
    __syncthreads();
    int beg = offsK[bin * NBLK] - EE;
    int cnt = cnt_s;
    for (int i = threadIdx.x; i < cnt; i += 256)
        atomicAdd(&curs[(pairsK[beg + i] >> 17) & 127], 1);
    __syncthreads();
    if (threadIdx.x == 0) {
        int run = 0;
        for (int j = 0; j < 128; ++j) {
            offs[j] = run;
            run += curs[j];
            curs[j] = offs[j];
        }
        offs[128] = run;
    }
    __syncthreads();
    for (int i = threadIdx.x; i < cnt; i += 256) {
        uint32_t u = pairsK[beg + i];
        int p = atomicAdd(&curs[(u >> 17) & 127], 1);
        list[p] = u;
    }
    __syncthreads();

    int w = threadIdx.x >> 6, lane = threadIdx.x & 63;
    int n0 = w * 32, n1 = n0 + 32;
    int e0 = offs[n0], e1 = offs[n1];
    uint32_t m = 0;
    int cur = n0;
    for (int e = e0; e < e1; e += 16) {
        int nb = e1 - e;
        uint32_t pr[16], v[16];
#pragma unroll
        for (int j = 0; j < 16; ++j)
            pr[j] = list[e + ((j < nb) ? j : (nb - 1))];
#pragma unroll
        for (int j = 0; j < 16; ++j)
            v[j] = hT16[(size_t)(pr[j] & 0x1FFFF) * 64 + lane];
#pragma unroll
        for (int j = 0; j < 16; ++j) {
            if (j < nb) {
                int d = (pr[j] >> 17) & 127;
                if (d != cur) {
                    buf[cur][lane] = (uint16_t)m;
                    cur = d;
                    m = 0;
                }
                m = max(m, v[j]);
            }
        }
    }
    buf[cur][lane] = (uint16_t)m;
    __syncthreads();
    int j0 = bin << 7;
    for (int f = threadIdx.x; f < 64 * 128; f += 256) {
        int c = f >> 7, j = f & 127;
        out[(size_t)c * NF + j0 + j] = __uint_as_float(((uint32_t)buf[j][c]) << 16);
    }
}

// ---------------------------------------------------------------------------
extern "C" void kernel_launch(void* const* d_in, const int* in_sizes, int n_in,
                              void* d_out, int out_size, void* d_ws, size_t ws_size,
                              hipStream_t stream)
{
    const float* a      = (const float*)d_in[0];
    const float* b      = (const float*)d_in[1];
    const float* Wself  = (const float*)d_in[2];
    const float* Wneigh = (const float*)d_in[3];
    const float* bias   = (const float*)d_in[4];
    const int* gather_i = (const int*)d_in[5];
    const int* reduce_i = (const int*)d_in[6];
    const int* up_src   = (const int*)d_in[7];
    const int* up_dst   = (const int*)d_in[8];
    float* out = (float*)d_out;

    // workspace layout (u32 elems); pairsE overlays hT (dead before gemm)
    uint32_t* xTb   = (uint32_t*)d_ws;                   // NN*64
    uint32_t* aggB  = xTb + (size_t)NN * 64;             // NN*64
    uint32_t* hT    = aggB + (size_t)NN * 64;            // NN*32
    uint32_t* pairsK= hT + (size_t)NN * 32;              // KK
    int* offs       = (int*)(pairsK + KK);               // NH+1 (combined E|K)
    int* bsum       = offs + (size_t)NH + 1;             // NSCB
    uint32_t* pairsE= hT;                                // EE (overlay)

    size_t need = ((size_t)NN * 160 + KK + (size_t)NH + 1 + NSCB) * 4;
    if (ws_size < need) return;  // fail visibly (output stays poisoned)

    // 1) fused transpose + histograms
    k_fused1<<<NTRB + 2 * NBLK, TPS, 0, stream>>>(a, b, xTb, reduce_i, up_dst, offs);

    // 2) scan
    k_bsum<<<NSCB, 256, 0, stream>>>(offs, bsum);
    k_final<<<NSCB, 256, 0, stream>>>(offs, bsum);

    // 3) pair scatter (long runs -> low write amp)
    k_pass2<<<2 * NBLK, TPS, 0, stream>>>(reduce_i, gather_i, up_dst, up_src,
                                          offs, pairsE, pairsK);

    // 4) bin-wise aggregation (in-LDS CSR, 16-deep register accumulate)
    k_aggcsr<<<NB_E, 256, 0, stream>>>(xTb, offs, pairsE, aggB);

    // 5) MFMA GEMM + bias + relu -> hT (bf16)
    k_gemm<<<512, 256, 0, stream>>>(xTb, aggB, Wself, Wneigh, bias, hT);

    // 6) bin-wise unpool max (in-LDS CSR, 16-deep register max)
    k_unpoolcsr<<<NB_K, 256, 0, stream>>>((const uint16_t*)hT, offs + KOFF,
                                          pairsK, out);
}

// Round 10
// 242.993 us; speedup vs baseline: 1.1202x; 1.1202x over previous
//
#include <hip/hip_runtime.h>
#include <stdint.h>

// Problem constants (fixed by the reference)
constexpr int NN = 131072;          // coarse nodes
constexpr int EE = 1048576;         // edges
constexpr int NF = 4 * NN;          // fine nodes = 524288
constexpr int KK = 3 * NF;          // unpool entries = 1572864

// coarse-bin sort configuration
constexpr int NSB  = 256;           // sort blocks per side
constexpr int TPS  = 1024;          // threads per sort block
constexpr int SHC_E = 9;            // 512 nodes/coarse-bin  -> 256 bins
constexpr int SHC_K = 10;           // 1024 fine/coarse-bin  -> 512 bins
constexpr int NBC_E = NN >> SHC_E;  // 256
constexpr int NBC_K = NF >> SHC_K;  // 512
constexpr int EPT_E = EE / NSB / TPS;   // 4
constexpr int EPT_K = KK / NSB / TPS;   // 6
constexpr int KOFF2 = NBC_E * NSB;      // 65536
constexpr int NH2   = KOFF2 + NBC_K * NSB;  // 196608
constexpr int NSCB  = NH2 / 2048;       // 96 scan blocks
constexpr int NTRB  = NN / 32 / 4;      // 1024 transpose blocks (4 tiles each)

// consumer slice caps (Poisson mean 512 / 384; caps are +22/+19 sigma)
constexpr int CAP_AG = 1024;
constexpr int CAP_UP = 896;

typedef __attribute__((ext_vector_type(8))) short bf16x8;
typedef __attribute__((ext_vector_type(4))) float f32x4;

__device__ inline uint32_t bf16rn(float f) {
    uint32_t u = __float_as_uint(f);
    return (u + 0x7FFFu + ((u >> 16) & 1u)) >> 16;
}
__device__ inline uint32_t pack2(float lo, float hi) {
    return bf16rn(lo) | (bf16rn(hi) << 16);
}
__device__ inline float bf_lo(uint32_t v) { return __uint_as_float(v << 16); }
__device__ inline float bf_hi(uint32_t v) { return __uint_as_float(v & 0xFFFF0000u); }

// ---------------------------------------------------------------------------
// 1) Fused: transpose (blocks 0..NTRB-1) + pass1 coarse histograms
// ---------------------------------------------------------------------------
template<int NB, int EPT>
__device__ void pass1_body(const int* __restrict__ idx, int shift,
                           int* __restrict__ histG, int blk, int* hist)
{
    for (int f = threadIdx.x; f < NB; f += TPS) hist[f] = 0;
    __syncthreads();
    int base = blk * (TPS * EPT);
#pragma unroll
    for (int u = 0; u < EPT; ++u) {
        int b = idx[base + u * TPS + threadIdx.x] >> shift;
        atomicAdd(&hist[b], 1);
    }
    __syncthreads();
    for (int f = threadIdx.x; f < NB; f += TPS)
        histG[f * NSB + blk] = hist[f];
}

__global__ __launch_bounds__(1024) void k_fused1(
    const float* __restrict__ a, const float* __restrict__ b,
    uint32_t* __restrict__ xTb,
    const int* __restrict__ reduce_i, const int* __restrict__ up_dst,
    int* __restrict__ histG)
{
    __shared__ int smem[128 * 33];   // union: float tile[128][33] / hist
    if (blockIdx.x < NTRB) {
        float (*tile)[33] = (float (*)[33])smem;
        for (int t = 0; t < 4; ++t) {
            int i0 = (blockIdx.x * 4 + t) * 32;
            for (int f = threadIdx.x; f < 128 * 32; f += TPS) {
                int c = f >> 5, j = f & 31;
                const float* src = (c < 64) ? a : b;
                tile[c][j] = src[(size_t)(c & 63) * NN + i0 + j];
            }
            __syncthreads();
            for (int f = threadIdx.x; f < 64 * 32; f += TPS) {
                int p = f & 63, j = f >> 6;
                xTb[(size_t)(i0 + j) * 64 + p] =
                    pack2(tile[2 * p][j], tile[2 * p + 1][j]);
            }
            __syncthreads();
        }
    } else if (blockIdx.x < NTRB + NSB) {
        pass1_body<NBC_E, EPT_E>(reduce_i, SHC_E, histG, blockIdx.x - NTRB, smem);
    } else {
        pass1_body<NBC_K, EPT_K>(up_dst, SHC_K, histG + KOFF2,
                                 blockIdx.x - NTRB - NSB, smem);
    }
}

// ---------------------------------------------------------------------------
// 2) Scan: block sums over 2048-chunks, then fused final scan
// ---------------------------------------------------------------------------
__global__ __launch_bounds__(256) void k_bsum(
    const int* __restrict__ cnt, int* __restrict__ bsum)
{
    __shared__ int s[256];
    int base = blockIdx.x * 2048;
    int sum = 0;
    for (int j = threadIdx.x; j < 2048; j += 256) sum += cnt[base + j];
    s[threadIdx.x] = sum;
    __syncthreads();
    for (int o = 128; o > 0; o >>= 1) {
        if (threadIdx.x < o) s[threadIdx.x] += s[threadIdx.x + o];
        __syncthreads();
    }
    if (threadIdx.x == 0) bsum[blockIdx.x] = s[0];
}

__global__ __launch_bounds__(256) void k_final(
    int* __restrict__ offs, const int* __restrict__ bsum)
{
    __shared__ int ts[256];
    int partial = 0;
    for (int i = threadIdx.x; i < blockIdx.x; i += 256) partial += bsum[i];
    ts[threadIdx.x] = partial;
    __syncthreads();
    for (int o = 128; o > 0; o >>= 1) {
        if (threadIdx.x < o) ts[threadIdx.x] += ts[threadIdx.x + o];
        __syncthreads();
    }
    int bb = ts[0];
    __syncthreads();

    int base = blockIdx.x * 2048 + threadIdx.x * 8;
    int loc[8];
    int sum = 0;
#pragma unroll
    for (int u = 0; u < 8; ++u) {
        int v = offs[base + u];
        loc[u] = sum;
        sum += v;
    }
    ts[threadIdx.x] = sum;
    __syncthreads();
    for (int o = 1; o < 256; o <<= 1) {
        int v = (threadIdx.x >= o) ? ts[threadIdx.x - o] : 0;
        __syncthreads();
        ts[threadIdx.x] += v;
        __syncthreads();
    }
    int texc = (threadIdx.x == 0) ? 0 : ts[threadIdx.x - 1];
#pragma unroll
    for (int u = 0; u < 8; ++u) offs[base + u] = bb + texc + loc[u];
    if (blockIdx.x == gridDim.x - 1 && threadIdx.x == 255) offs[NH2] = bb + ts[255];
}

// ---------------------------------------------------------------------------
// 3) pass2: scatter packed pairs into coarse-bin regions.
//    runs of 16 (E) / 12 (K) entries -> write amp ~2x; full grid occupancy.
//    pack: payload (17 bits) | coarse-bin-local (<<17, 9 or 10 bits)
// ---------------------------------------------------------------------------
template<int NB, int EPT>
__device__ void pass2_body(const int* __restrict__ idx,
                           const int* __restrict__ payload, int shift,
                           const int* __restrict__ offsG, int sub,
                           uint32_t* __restrict__ pairs, int blk, int* curs)
{
    int lmask = (1 << shift) - 1;
    for (int f = threadIdx.x; f < NB; f += TPS)
        curs[f] = offsG[f * NSB + blk] - sub;
    __syncthreads();
    int base = blk * (TPS * EPT);
#pragma unroll
    for (int u = 0; u < EPT; ++u) {
        int e = base + u * TPS + threadIdx.x;
        int bk = idx[e];
        int pos = atomicAdd(&curs[bk >> shift], 1);
        pairs[pos] = (uint32_t)payload[e] | ((uint32_t)(bk & lmask) << 17);
    }
}

__global__ __launch_bounds__(1024) void k_pass2(
    const int* __restrict__ reduce_i, const int* __restrict__ gather_i,
    const int* __restrict__ up_dst, const int* __restrict__ up_src,
    const int* __restrict__ offs,
    uint32_t* __restrict__ pairsE, uint32_t* __restrict__ pairsK)
{
    __shared__ int curs[NBC_K];   // 2 KB
    if (blockIdx.x < NSB)
        pass2_body<NBC_E, EPT_E>(reduce_i, gather_i, SHC_E, offs, 0,
                                 pairsE, blockIdx.x, curs);
    else
        pass2_body<NBC_K, EPT_K>(up_dst, up_src, SHC_K, offs + KOFF2, EE,
                                 pairsK, blockIdx.x - NSB, curs);
}

// ---------------------------------------------------------------------------
// 4) Aggregation: 8 blocks per coarse bin; stream+filter (ballot append),
//    in-LDS counting sort, 16-deep MLP register accumulate, write-once.
// ---------------------------------------------------------------------------
__global__ __launch_bounds__(256) void k_aggcsr(
    const uint32_t* __restrict__ xTb, const int* __restrict__ offs,
    const uint32_t* __restrict__ pairsE, uint32_t* __restrict__ aggB)
{
    __shared__ uint32_t stage[CAP_AG];
    __shared__ uint32_t list[CAP_AG];
    __shared__ int loffs[65];
    __shared__ int curs[64];
    __shared__ int nstage;
    int binc = blockIdx.x >> 3, sub = blockIdx.x & 7;
    int beg = offs[binc * NSB], end = offs[(binc + 1) * NSB];
    if (threadIdx.x == 0) nstage = 0;
    if (threadIdx.x < 64) curs[threadIdx.x] = 0;
    __syncthreads();
    int lane = threadIdx.x & 63;

    // stream the coarse-bin region; keep entries for local nodes [sub*64, +64)
    for (int i0 = beg; i0 < end; i0 += 256) {
        int i = i0 + threadIdx.x;
        bool mine = false;
        uint32_t ent = 0;
        if (i < end) {
            uint32_t u = pairsE[i];
            int loc = u >> 17;                     // 9-bit local node
            mine = (loc >> 6) == sub;
            ent = (u & 0x1FFFFu) | ((uint32_t)(loc & 63) << 17);
        }
        unsigned long long mask = __ballot(mine);
        if (mask) {
            int leader = __ffsll(mask) - 1;
            int rank = __popcll(mask & ((1ull << lane) - 1ull));
            int wb = 0;
            if (lane == leader) wb = atomicAdd(&nstage, (int)__popcll(mask));
            wb = __shfl(wb, leader);
            int p = wb + rank;
            if (mine && p < CAP_AG) stage[p] = ent;
        }
    }
    __syncthreads();
    int cnt = min(nstage, CAP_AG);
    for (int i = threadIdx.x; i < cnt; i += 256)
        atomicAdd(&curs[stage[i] >> 17], 1);
    __syncthreads();
    if (threadIdx.x == 0) {
        int run = 0;
        for (int j = 0; j < 64; ++j) {
            loffs[j] = run;
            run += curs[j];
            curs[j] = loffs[j];
        }
        loffs[64] = run;
    }
    __syncthreads();
    for (int i = threadIdx.x; i < cnt; i += 256) {
        uint32_t u = stage[i];
        int p = atomicAdd(&curs[u >> 17], 1);
        list[p] = u;
    }
    __syncthreads();

    // 16-deep MLP consume; wave owns 16 of the block's 64 nodes
    int w = threadIdx.x >> 6;
    int n0 = w * 16, n1 = n0 + 16;
    int e0 = loffs[n0], e1 = loffs[n1];
    size_t rowbase = (size_t)(binc * 512 + sub * 64) * 64 + lane;
    float sx = 0.f, sy = 0.f;
    int cur = n0;
    for (int e = e0; e < e1; e += 16) {
        int nb = e1 - e;
        uint32_t pr[16], v[16];
#pragma unroll
        for (int j = 0; j < 16; ++j)
            pr[j] = list[e + ((j < nb) ? j : (nb - 1))];
#pragma unroll
        for (int j = 0; j < 16; ++j)
            v[j] = xTb[(size_t)(pr[j] & 0x1FFFF) * 64 + lane];
#pragma unroll
        for (int j = 0; j < 16; ++j) {
            if (j < nb) {
                int d = pr[j] >> 17;
                if (d != cur) {
                    aggB[rowbase + (size_t)cur * 64] = pack2(sx, sy);
                    for (int z = cur + 1; z < d; ++z)
                        aggB[rowbase + (size_t)z * 64] = 0u;
                    cur = d;
                    sx = 0.f; sy = 0.f;
                }
                sx += bf_lo(v[j]);
                sy += bf_hi(v[j]);
            }
        }
    }
    aggB[rowbase + (size_t)cur * 64] = pack2(sx, sy);
    for (int z = cur + 1; z < n1; ++z)
        aggB[rowbase + (size_t)z * 64] = 0u;
}

// ---------------------------------------------------------------------------
// 5) MFMA GEMM: h = relu([Wself|Wneigh] @ [x;agg] + bias), bf16 in/out.
//    C/D: col(node)=l&15, row(c)=(l>>4)*4+r  [m89-verified layout]
// ---------------------------------------------------------------------------
__global__ __launch_bounds__(256) void k_gemm(
    const uint32_t* __restrict__ xTb, const uint32_t* __restrict__ aggB,
    const float* __restrict__ Wself, const float* __restrict__ Wneigh,
    const float* __restrict__ bias, uint32_t* __restrict__ hT)
{
    int lane = threadIdx.x & 63;
    int wid = blockIdx.x * 4 + (threadIdx.x >> 6);
    int lr = lane & 15, lq = lane >> 4;

    bf16x8 wf[4][8];
#pragma unroll
    for (int mt = 0; mt < 4; ++mt) {
#pragma unroll
        for (int kt = 0; kt < 8; ++kt) {
            const float* W = (kt < 4) ? Wself : Wneigh;
            const float* p = W + (size_t)(mt * 16 + lr) * 128 + (kt & 3) * 32 + lq * 8;
            bf16x8 v;
#pragma unroll
            for (int j = 0; j < 8; ++j) v[j] = (short)bf16rn(p[j]);
            wf[mt][kt] = v;
        }
    }
    float bv[4][4];
#pragma unroll
    for (int mt = 0; mt < 4; ++mt)
#pragma unroll
        for (int r = 0; r < 4; ++r)
            bv[mt][r] = bias[mt * 16 + lq * 4 + r];

    const int NG = NN / 16;
    int stride = gridDim.x * 4;
    for (int g = wid; g < NG; g += stride) {
        int n = g * 16 + lr;
        const uint32_t* xr = xTb + (size_t)n * 64 + lq * 4;
        const uint32_t* ar = aggB + (size_t)n * 64 + lq * 4;
        bf16x8 bq[8];
#pragma unroll
        for (int kt = 0; kt < 4; ++kt)
            bq[kt] = *reinterpret_cast<const bf16x8*>(xr + kt * 16);
#pragma unroll
        for (int kt = 0; kt < 4; ++kt)
            bq[4 + kt] = *reinterpret_cast<const bf16x8*>(ar + kt * 16);
#pragma unroll
        for (int mt = 0; mt < 4; ++mt) {
            f32x4 acc = {0.f, 0.f, 0.f, 0.f};
#pragma unroll
            for (int kt = 0; kt < 8; ++kt)
                acc = __builtin_amdgcn_mfma_f32_16x16x32_bf16(wf[mt][kt], bq[kt], acc, 0, 0, 0);
            uint32_t u0 = pack2(fmaxf(acc[0] + bv[mt][0], 0.f), fmaxf(acc[1] + bv[mt][1], 0.f));
            uint32_t u1 = pack2(fmaxf(acc[2] + bv[mt][2], 0.f), fmaxf(acc[3] + bv[mt][3], 0.f));
            *reinterpret_cast<uint2*>(hT + (size_t)n * 32 + mt * 8 + lq * 2) = make_uint2(u0, u1);
        }
    }
}

// ---------------------------------------------------------------------------
// 6) Unpool: 8 blocks per coarse K-bin; stream+filter, in-LDS sort,
//    16-deep MLP register bit-max (bf16 >= 0), coalesced epilogue.
// ---------------------------------------------------------------------------
__global__ __launch_bounds__(256) void k_unpoolcsr(
    const uint16_t* __restrict__ hT16, const int* __restrict__ offsK,
    const uint32_t* __restrict__ pairsK, float* __restrict__ out)
{
    __shared__ uint32_t stage[CAP_UP];
    __shared__ uint32_t list[CAP_UP];
    __shared__ int loffs[129];
    __shared__ int curs[128];
    __shared__ uint16_t buf[128][65];
    __shared__ int nstage;
    int binc = blockIdx.x >> 3, sub = blockIdx.x & 7;
    int beg = offsK[binc * NSB] - EE, end = offsK[(binc + 1) * NSB] - EE;
    if (threadIdx.x == 0) nstage = 0;
    if (threadIdx.x < 128) curs[threadIdx.x] = 0;
    for (int f = threadIdx.x; f < 128 * 65; f += 256) ((uint16_t*)buf)[f] = 0;
    __syncthreads();
    int lane = threadIdx.x & 63;

    for (int i0 = beg; i0 < end; i0 += 256) {
        int i = i0 + threadIdx.x;
        bool mine = false;
        uint32_t ent = 0;
        if (i < end) {
            uint32_t u = pairsK[i];
            int loc = u >> 17;                     // 10-bit local fine node
            mine = (loc >> 7) == sub;
            ent = (u & 0x1FFFFu) | ((uint32_t)(loc & 127) << 17);
        }
        unsigned long long mask = __ballot(mine);
        if (mask) {
            int leader = __ffsll(mask) - 1;
            int rank = __popcll(mask & ((1ull << lane) - 1ull));
            int wb = 0;
            if (lane == leader) wb = atomicAdd(&nstage, (int)__popcll(mask));
            wb = __shfl(wb, leader);
            int p = wb + rank;
            if (mine && p < CAP_UP) stage[p] = ent;
        }
    }
    __syncthreads();
    int cnt = min(nstage, CAP_UP);
    for (int i = threadIdx.x; i < cnt; i += 256)
        atomicAdd(&curs[stage[i] >> 17], 1);
    __syncthreads();
    if (threadIdx.x == 0) {
        int run = 0;
        for (int j = 0; j < 128; ++j) {
            loffs[j] = run;
            run += curs[j];
            curs[j] = loffs[j];
        }
        loffs[128] = run;
    }
    __syncthreads();
    for (int i = threadIdx.x; i < cnt; i += 256) {
        uint32_t u = stage[i];
        int p = atomicAdd(&curs[u >> 17], 1);
        list[p] = u;
    }
    __syncthreads();

    int w = threadIdx.x >> 6;
    int n0 = w * 32, n1 = n0 + 32;
    int e0 = loffs[n0], e1 = loffs[n1];
    uint32_t m = 0;
    int cur = n0;
    for (int e = e0; e < e1; e += 16) {
        int nb = e1 - e;
        uint32_t pr[16], v[16];
#pragma unroll
        for (int j = 0; j < 16; ++j)
            pr[j] = list[e + ((j < nb) ? j : (nb - 1))];
#pragma unroll
        for (int j = 0; j < 16; ++j)
            v[j] = hT16[(size_t)(pr[j] & 0x1FFFF) * 64 + lane];
#pragma unroll
        for (int j = 0; j < 16; ++j) {
            if (j < nb) {
                int d = pr[j] >> 17;
                if (d != cur) {
                    buf[cur][lane] = (uint16_t)m;
                    cur = d;
                    m = 0;
                }
                m = max(m, v[j]);
            }
        }
    }
    buf[cur][lane] = (uint16_t)m;
    __syncthreads();
    int j0 = binc * 1024 + sub * 128;
    for (int f = threadIdx.x; f < 64 * 128; f += 256) {
        int c = f >> 7, j = f & 127;
        out[(size_t)c * NF + j0 + j] = __uint_as_float(((uint32_t)buf[j][c]) << 16);
    }
}

// ---------------------------------------------------------------------------
extern "C" void kernel_launch(void* const* d_in, const int* in_sizes, int n_in,
                              void* d_out, int out_size, void* d_ws, size_t ws_size,
                              hipStream_t stream)
{
    const float* a      = (const float*)d_in[0];
    const float* b      = (const float*)d_in[1];
    const float* Wself  = (const float*)d_in[2];
    const float* Wneigh = (const float*)d_in[3];
    const float* bias   = (const float*)d_in[4];
    const int* gather_i = (const int*)d_in[5];
    const int* reduce_i = (const int*)d_in[6];
    const int* up_src   = (const int*)d_in[7];
    const int* up_dst   = (const int*)d_in[8];
    float* out = (float*)d_out;

    // workspace layout (u32 elems); pairsE overlays hT (dead before gemm)
    uint32_t* xTb   = (uint32_t*)d_ws;                   // NN*64
    uint32_t* aggB  = xTb + (size_t)NN * 64;             // NN*64
    uint32_t* hT    = aggB + (size_t)NN * 64;            // NN*32
    uint32_t* pairsK= hT + (size_t)NN * 32;              // KK
    int* offs       = (int*)(pairsK + KK);               // NH2+1 (combined E|K)
    int* bsum       = offs + (size_t)NH2 + 1;            // NSCB
    uint32_t* pairsE= hT;                                // EE (overlay)

    size_t need = ((size_t)NN * 160 + KK + (size_t)NH2 + 1 + NSCB) * 4;
    if (ws_size < need) return;  // fail visibly (output stays poisoned)

    // 1) fused transpose + coarse histograms
    k_fused1<<<NTRB + 2 * NSB, TPS, 0, stream>>>(a, b, xTb, reduce_i, up_dst, offs);

    // 2) scan
    k_bsum<<<NSCB, 256, 0, stream>>>(offs, bsum);
    k_final<<<NSCB, 256, 0, stream>>>(offs, bsum);

    // 3) pair scatter into coarse-bin regions (long runs, full occupancy)
    k_pass2<<<2 * NSB, TPS, 0, stream>>>(reduce_i, gather_i, up_dst, up_src,
                                         offs, pairsE, pairsK);

    // 4) aggregation (8 blocks/coarse-bin, stream+filter, register accumulate)
    k_aggcsr<<<8 * NBC_E, 256, 0, stream>>>(xTb, offs, pairsE, aggB);

    // 5) MFMA GEMM + bias + relu -> hT (bf16)
    k_gemm<<<512, 256, 0, stream>>>(xTb, aggB, Wself, Wneigh, bias, hT);

    // 6) unpool max (8 blocks/coarse-bin, stream+filter, register max)
    k_unpoolcsr<<<8 * NBC_K, 256, 0, stream>>>((const uint16_t*)hT, offs + KOFF2,
                                               pairsK, out);
}